// Round 1
// baseline (331.886 us; speedup 1.0000x reference)
//
#include <hip/hip_runtime.h>
#include <hip/hip_bf16.h>
#include <math.h>

namespace {
constexpr int B  = 4;
constexpr int T  = 2048;
constexpr int C  = 512;
constexpr int H  = 8;
constexpr int Dh = 64;
constexpr int R  = 16;
constexpr int Nr = 128;   // T / R
constexpr int K  = 8;     // top-k regions
constexpr int BT = B * T;        // 8192
constexpr int QKV_N = 3 * C;     // 1536
constexpr float SCALE = 0.125f;  // 1/sqrt(Dh)
}

// ---------------------------------------------------------------------------
// QKV GEMM: (BT x C) @ (C x 3C) + bias, scattered into q/k/v (B,H,T,Dh)
// 64x64 tile, BK=32, 256 threads, 4x4 microtile.
// ---------------------------------------------------------------------------
__global__ __launch_bounds__(256) void qkv_gemm_kernel(
    const float* __restrict__ X, const float* __restrict__ W,
    const float* __restrict__ bias,
    float* __restrict__ qb, float* __restrict__ kb, float* __restrict__ vb)
{
  __shared__ float As[32][68];  // As[k][m] (transposed on store)
  __shared__ float Bs[32][68];  // Bs[k][n]
  const int tid = threadIdx.x;
  const int bm = blockIdx.y * 64;
  const int bn = blockIdx.x * 64;
  const int tm4 = (tid >> 4) << 2;
  const int tn4 = (tid & 15) << 2;
  const int arow = tid >> 3;          // 0..31
  const int acol = (tid & 7) << 2;    // 0..28
  const int brow = tid >> 4;          // 0..15
  const int bcol = (tid & 15) << 2;   // 0..60
  float acc[4][4] = {};
  for (int k0 = 0; k0 < C; k0 += 32) {
#pragma unroll
    for (int p = 0; p < 2; ++p) {
      const float4 a = *(const float4*)&X[(size_t)(bm + arow + 32 * p) * C + (k0 + acol)];
      As[acol + 0][arow + 32 * p] = a.x;
      As[acol + 1][arow + 32 * p] = a.y;
      As[acol + 2][arow + 32 * p] = a.z;
      As[acol + 3][arow + 32 * p] = a.w;
    }
#pragma unroll
    for (int p = 0; p < 2; ++p) {
      *(float4*)&Bs[brow + 16 * p][bcol] =
          *(const float4*)&W[(size_t)(k0 + brow + 16 * p) * QKV_N + (bn + bcol)];
    }
    __syncthreads();
#pragma unroll
    for (int kk = 0; kk < 32; ++kk) {
      const float4 av = *(const float4*)&As[kk][tm4];
      const float4 bv = *(const float4*)&Bs[kk][tn4];
      const float a[4] = {av.x, av.y, av.z, av.w};
      const float bb[4] = {bv.x, bv.y, bv.z, bv.w};
#pragma unroll
      for (int i = 0; i < 4; ++i)
#pragma unroll
        for (int j = 0; j < 4; ++j) acc[i][j] += a[i] * bb[j];
    }
    __syncthreads();
  }
  // epilogue: n-tile (64 wide, 64-aligned) lies in exactly one (s,h) pair
  const int s  = bn >> 9;
  const int h  = (bn >> 6) & 7;
  const int b  = bm >> 11;
  const int t0 = bm & (T - 1);
  float* dst = (s == 0) ? qb : (s == 1) ? kb : vb;
  const float4 bi = *(const float4*)&bias[bn + tn4];
#pragma unroll
  for (int i = 0; i < 4; ++i) {
    const int t = t0 + tm4 + i;
    float4 o;
    o.x = acc[i][0] + bi.x; o.y = acc[i][1] + bi.y;
    o.z = acc[i][2] + bi.z; o.w = acc[i][3] + bi.w;
    *(float4*)&dst[((size_t)(b * H + h) * T + t) * Dh + tn4] = o;
  }
}

// ---------------------------------------------------------------------------
// Region means of q and k: (B,H,Nr,Dh)
// ---------------------------------------------------------------------------
__global__ __launch_bounds__(64) void region_avg_kernel(
    const float* __restrict__ qb, const float* __restrict__ kb,
    float* __restrict__ qavg, float* __restrict__ kavg)
{
  const int blk = blockIdx.x;   // bh*Nr + n  (contiguous: base = blk*R*Dh)
  const int d = threadIdx.x;
  const float* qp = qb + (size_t)blk * R * Dh;
  const float* kp = kb + (size_t)blk * R * Dh;
  float sq = 0.f, sk = 0.f;
#pragma unroll
  for (int r = 0; r < R; ++r) { sq += qp[r * Dh + d]; sk += kp[r * Dh + d]; }
  qavg[(size_t)blk * Dh + d] = sq * (1.f / 16.f);
  kavg[(size_t)blk * Dh + d] = sk * (1.f / 16.f);
}

// ---------------------------------------------------------------------------
// Region scores (128 per query region) + top-8 (ties: lowest index, like jax)
// One block per (b,h,nq), 128 threads.
// ---------------------------------------------------------------------------
__global__ __launch_bounds__(128) void topk_kernel(
    const float* __restrict__ qavg, const float* __restrict__ kavg,
    int* __restrict__ topk)
{
  const int blk = blockIdx.x;       // bh*Nr + nq
  const int bh  = blk >> 7;
  const int m   = threadIdx.x;      // key region index
  __shared__ float qrow[Dh];
  __shared__ float sc[Nr];
  __shared__ float rv[Nr];
  __shared__ int   ri[Nr];
  __shared__ int   sel[K];
  if (m < Dh) qrow[m] = qavg[(size_t)blk * Dh + m];
  __syncthreads();
  const float* krow = kavg + ((size_t)bh * Nr + m) * Dh;
  float dot = 0.f;
#pragma unroll
  for (int i = 0; i < Dh; ++i) dot += qrow[i] * krow[i];
  sc[m] = dot;   // positive scale doesn't change ordering
  bool taken = false;
  __syncthreads();
  for (int j = 0; j < K; ++j) {
    rv[m] = taken ? -INFINITY : sc[m];
    ri[m] = m;
    __syncthreads();
    for (int off = 64; off >= 1; off >>= 1) {
      if (m < off) {
        const float v2 = rv[m + off]; const int i2 = ri[m + off];
        if (v2 > rv[m] || (v2 == rv[m] && i2 < ri[m])) { rv[m] = v2; ri[m] = i2; }
      }
      __syncthreads();
    }
    if (m == 0) sel[j] = ri[0];
    __syncthreads();
    if (m == sel[j]) taken = true;
  }
  if (m < K) topk[blk * K + m] = sel[m];
}

// ---------------------------------------------------------------------------
// Block-sparse attention. One block per (b,h,n): q 16x64, gather 8 regions of
// K (then reuse same LDS for V), logits 16x128, softmax, PV, write (B,T,C).
// ---------------------------------------------------------------------------
__global__ __launch_bounds__(256) void attn_kernel(
    const float* __restrict__ qb, const float* __restrict__ kb,
    const float* __restrict__ vb, const int* __restrict__ topk,
    float* __restrict__ aout)
{
  const int blk = blockIdx.x;     // bh*Nr + n
  const int bh  = blk >> 7;
  const int n   = blk & (Nr - 1);
  const int b   = bh >> 3;
  const int h   = bh & 7;
  const int tid = threadIdx.x;
  __shared__ float qs[R][68];
  __shared__ float kvs[K * R][68];   // K first, reused for V
  __shared__ float lg[R][K * R];
  __shared__ int ridx[K];
  if (tid < K) ridx[tid] = topk[blk * K + tid];
  {
    const int r = tid >> 4, c4 = (tid & 15) << 2;
    *(float4*)&qs[r][c4] =
        *(const float4*)&qb[((size_t)bh * T + n * R + r) * Dh + c4];
  }
  __syncthreads();
  // stage K regions
#pragma unroll
  for (int p = 0; p < 8; ++p) {
    const int f = p * 256 + tid;
    const int row = f >> 4, c4 = (f & 15) << 2;
    const int reg = row >> 4, rr = row & 15;
    *(float4*)&kvs[row][c4] =
        *(const float4*)&kb[((size_t)bh * T + ridx[reg] * R + rr) * Dh + c4];
  }
  __syncthreads();
  // QK^T + in-register online softmax: thread owns row r, cols g+16j
  const int r = tid >> 4;
  const int g = tid & 15;
  float p8[8];
#pragma unroll
  for (int j = 0; j < 8; ++j) {
    const int c = g + 16 * j;
    float dot = 0.f;
#pragma unroll
    for (int i = 0; i < Dh; ++i) dot += qs[r][i] * kvs[c][i];
    p8[j] = dot * SCALE;
  }
  float mx = p8[0];
#pragma unroll
  for (int j = 1; j < 8; ++j) mx = fmaxf(mx, p8[j]);
#pragma unroll
  for (int off = 1; off < 16; off <<= 1) mx = fmaxf(mx, __shfl_xor(mx, off));
  float sum = 0.f;
#pragma unroll
  for (int j = 0; j < 8; ++j) { p8[j] = __expf(p8[j] - mx); sum += p8[j]; }
#pragma unroll
  for (int off = 1; off < 16; off <<= 1) sum += __shfl_xor(sum, off);
  const float inv = 1.f / sum;
#pragma unroll
  for (int j = 0; j < 8; ++j) lg[r][g + 16 * j] = p8[j] * inv;
  __syncthreads();   // all QK reads done -> safe to overwrite kvs with V
#pragma unroll
  for (int p = 0; p < 8; ++p) {
    const int f = p * 256 + tid;
    const int row = f >> 4, c4 = (f & 15) << 2;
    const int reg = row >> 4, rr = row & 15;
    *(float4*)&kvs[row][c4] =
        *(const float4*)&vb[((size_t)bh * T + ridx[reg] * R + rr) * Dh + c4];
  }
  __syncthreads();
  // PV: thread owns row r, output cols d0..d0+3
  const int d0 = g << 2;
  float o0 = 0.f, o1 = 0.f, o2 = 0.f, o3 = 0.f;
#pragma unroll 4
  for (int c = 0; c < K * R; ++c) {
    const float w = lg[r][c];
    const float4 vv = *(const float4*)&kvs[c][d0];
    o0 += w * vv.x; o1 += w * vv.y; o2 += w * vv.z; o3 += w * vv.w;
  }
  float4 o = {o0, o1, o2, o3};
  *(float4*)&aout[((size_t)b * T + n * R + r) * C + h * Dh + d0] = o;
}

// ---------------------------------------------------------------------------
// Output GEMM: (BT x C) @ (C x C) + bias -> d_out
// ---------------------------------------------------------------------------
__global__ __launch_bounds__(256) void out_gemm_kernel(
    const float* __restrict__ A, const float* __restrict__ W,
    const float* __restrict__ bias, float* __restrict__ out)
{
  __shared__ float As[32][68];
  __shared__ float Bs[32][68];
  const int tid = threadIdx.x;
  const int bm = blockIdx.y * 64;
  const int bn = blockIdx.x * 64;
  const int tm4 = (tid >> 4) << 2;
  const int tn4 = (tid & 15) << 2;
  const int arow = tid >> 3;
  const int acol = (tid & 7) << 2;
  const int brow = tid >> 4;
  const int bcol = (tid & 15) << 2;
  float acc[4][4] = {};
  for (int k0 = 0; k0 < C; k0 += 32) {
#pragma unroll
    for (int p = 0; p < 2; ++p) {
      const float4 a = *(const float4*)&A[(size_t)(bm + arow + 32 * p) * C + (k0 + acol)];
      As[acol + 0][arow + 32 * p] = a.x;
      As[acol + 1][arow + 32 * p] = a.y;
      As[acol + 2][arow + 32 * p] = a.z;
      As[acol + 3][arow + 32 * p] = a.w;
    }
#pragma unroll
    for (int p = 0; p < 2; ++p) {
      *(float4*)&Bs[brow + 16 * p][bcol] =
          *(const float4*)&W[(size_t)(k0 + brow + 16 * p) * C + (bn + bcol)];
    }
    __syncthreads();
#pragma unroll
    for (int kk = 0; kk < 32; ++kk) {
      const float4 av = *(const float4*)&As[kk][tm4];
      const float4 bv = *(const float4*)&Bs[kk][tn4];
      const float a[4] = {av.x, av.y, av.z, av.w};
      const float bb[4] = {bv.x, bv.y, bv.z, bv.w};
#pragma unroll
      for (int i = 0; i < 4; ++i)
#pragma unroll
        for (int j = 0; j < 4; ++j) acc[i][j] += a[i] * bb[j];
    }
    __syncthreads();
  }
  const float4 bi = *(const float4*)&bias[bn + tn4];
#pragma unroll
  for (int i = 0; i < 4; ++i) {
    const int m = bm + tm4 + i;
    float4 o;
    o.x = acc[i][0] + bi.x; o.y = acc[i][1] + bi.y;
    o.z = acc[i][2] + bi.z; o.w = acc[i][3] + bi.w;
    *(float4*)&out[(size_t)m * C + bn + tn4] = o;
  }
}

extern "C" void kernel_launch(void* const* d_in, const int* in_sizes, int n_in,
                              void* d_out, int out_size, void* d_ws, size_t ws_size,
                              hipStream_t stream) {
  const float* x    = (const float*)d_in[0];
  const float* Wqkv = (const float*)d_in[1];
  const float* bqkv = (const float*)d_in[2];
  const float* Wout = (const float*)d_in[3];
  const float* bout = (const float*)d_in[4];
  float* out = (float*)d_out;

  float* ws   = (float*)d_ws;
  const size_t bhtd = (size_t)B * H * T * Dh;   // 4,194,304
  float* qb   = ws;
  float* kb   = qb + bhtd;
  float* vb   = kb + bhtd;
  float* qavg = vb + bhtd;
  float* kavg = qavg + (size_t)B * H * Nr * Dh;
  float* aout = kavg + (size_t)B * H * Nr * Dh;
  int*   topk = (int*)(aout + (size_t)B * T * C);

  qkv_gemm_kernel<<<dim3(QKV_N / 64, BT / 64), 256, 0, stream>>>(x, Wqkv, bqkv, qb, kb, vb);
  region_avg_kernel<<<B * H * Nr, 64, 0, stream>>>(qb, kb, qavg, kavg);
  topk_kernel<<<B * H * Nr, 128, 0, stream>>>(qavg, kavg, topk);
  attn_kernel<<<B * H * Nr, 256, 0, stream>>>(qb, kb, vb, topk, aout);
  out_gemm_kernel<<<dim3(C / 64, BT / 64), 256, 0, stream>>>(aout, Wout, bout, out);
}

// Round 2
// 167.471 us; speedup vs baseline: 1.9818x; 1.9818x over previous
//
#include <hip/hip_runtime.h>
#include <hip/hip_bf16.h>
#include <math.h>

typedef __bf16 bf16x8 __attribute__((ext_vector_type(8)));
typedef float f32x4 __attribute__((ext_vector_type(4)));

namespace {
constexpr int B  = 4;
constexpr int T  = 2048;
constexpr int C  = 512;
constexpr int H  = 8;
constexpr int Dh = 64;
constexpr int R  = 16;
constexpr int Nr = 128;   // T / R
constexpr int K  = 8;     // top-k regions
constexpr int BT = B * T;        // 8192
constexpr int QKV_N = 3 * C;     // 1536
constexpr int KD = 512;          // GEMM inner depth (= C)
constexpr float SCALE = 0.125f;  // 1/sqrt(Dh)
}

static __device__ __forceinline__ unsigned short f2bf(float f) {
  unsigned int u = __float_as_uint(f);
  u += 0x7fffu + ((u >> 16) & 1u);   // RNE
  return (unsigned short)(u >> 16);
}

static __device__ __forceinline__ void gload16(const unsigned short* g, unsigned short* l) {
  __builtin_amdgcn_global_load_lds(
      (const __attribute__((address_space(1))) unsigned int*)g,
      (__attribute__((address_space(3))) unsigned int*)l, 16, 0, 0);
}

// ---------------------------------------------------------------------------
// x (f32) -> xbf (bf16), elementwise
// ---------------------------------------------------------------------------
__global__ __launch_bounds__(256) void convert_x_kernel(
    const float4* __restrict__ x, ushort4* __restrict__ xbf) {
  const int i = blockIdx.x * 256 + threadIdx.x;
  const float4 v = x[i];
  ushort4 o;
  o.x = f2bf(v.x); o.y = f2bf(v.y); o.z = f2bf(v.z); o.w = f2bf(v.w);
  xbf[i] = o;
}

// ---------------------------------------------------------------------------
// W (Kd x Nd f32, row-major) -> Wt (Nd x Kd bf16)  [transpose + convert]
// ---------------------------------------------------------------------------
__global__ __launch_bounds__(256) void transpose_convert_kernel(
    const float* __restrict__ W, unsigned short* __restrict__ Wt, int Kd, int Nd) {
  __shared__ float tile[32][33];
  const int n0 = blockIdx.x * 32, k0 = blockIdx.y * 32;
  const int tx = threadIdx.x & 31, ty = threadIdx.x >> 5;   // ty 0..7
#pragma unroll
  for (int i = 0; i < 32; i += 8)
    tile[ty + i][tx] = W[(size_t)(k0 + ty + i) * Nd + (n0 + tx)];
  __syncthreads();
#pragma unroll
  for (int i = 0; i < 32; i += 8)
    Wt[(size_t)(n0 + ty + i) * Kd + (k0 + tx)] = f2bf(tile[tx][ty + i]);
}

// ---------------------------------------------------------------------------
// Shared bf16-MFMA mainloop: 128x128 tile, BK=32, 4 waves, each wave 64x64.
// A: [m][k] bf16 row-major (stride KD); Bt: [n][k] bf16 (stride KD).
// ---------------------------------------------------------------------------
__device__ __forceinline__ void mfma_mainloop(
    const unsigned short* __restrict__ A, const unsigned short* __restrict__ Bt,
    int bm, int bn, unsigned short* As, unsigned short* Bs, f32x4 (&acc)[4][4]) {
  const int tid = threadIdx.x;
  const int wave = tid >> 6, lane = tid & 63;
  const int wr = wave >> 1, wc = wave & 1;
  // staging: inst j in {0,1}: rows j*64 + wave*16 + lane/4, k-offset (lane&3)*8
  const unsigned short* ga = A  + (size_t)(bm + wave * 16 + (lane >> 2)) * KD + (lane & 3) * 8;
  const unsigned short* gb = Bt + (size_t)(bn + wave * 16 + (lane >> 2)) * KD + (lane & 3) * 8;
  unsigned short* lA = As + wave * 512;   // wave-uniform LDS bases (HW adds lane*16B)
  unsigned short* lB = Bs + wave * 512;
  const int fr = lane & 15, kg = lane >> 4;
  const unsigned short* rA = As + (wr * 64 + fr) * 32 + kg * 8;
  const unsigned short* rB = Bs + (wc * 64 + fr) * 32 + kg * 8;
  for (int k0 = 0; k0 < KD; k0 += 32) {
    gload16(ga + k0,                    lA);
    gload16(ga + (size_t)64 * KD + k0,  lA + 2048);
    gload16(gb + k0,                    lB);
    gload16(gb + (size_t)64 * KD + k0,  lB + 2048);
    __syncthreads();   // compiler drains vmcnt before barrier -> LDS ready
    bf16x8 a[4], b[4];
#pragma unroll
    for (int m = 0; m < 4; ++m) a[m] = *(const bf16x8*)(rA + m * 512);
#pragma unroll
    for (int n = 0; n < 4; ++n) b[n] = *(const bf16x8*)(rB + n * 512);
#pragma unroll
    for (int m = 0; m < 4; ++m)
#pragma unroll
      for (int n = 0; n < 4; ++n)
        acc[m][n] = __builtin_amdgcn_mfma_f32_16x16x32_bf16(a[m], b[n], acc[m][n], 0, 0, 0);
    __syncthreads();
  }
}

// ---------------------------------------------------------------------------
// QKV GEMM (bf16 MFMA): (BT x KD) @ (KD x 3C) + bias -> scatter f32 q/k/v
// ---------------------------------------------------------------------------
__global__ __launch_bounds__(256) void qkv_gemm_mfma_kernel(
    const unsigned short* __restrict__ xbf, const unsigned short* __restrict__ Wt,
    const float* __restrict__ bias,
    float* __restrict__ qb, float* __restrict__ kb, float* __restrict__ vb) {
  __shared__ unsigned short As[128 * 32];
  __shared__ unsigned short Bs[128 * 32];
  f32x4 acc[4][4] = {};
  const int bm = blockIdx.y * 128, bn = blockIdx.x * 128;
  mfma_mainloop(xbf, Wt, bm, bn, As, Bs, acc);
  const int lane = threadIdx.x & 63, wave = threadIdx.x >> 6;
  const int wr = wave >> 1, wc = wave & 1;
#pragma unroll
  for (int n = 0; n < 4; ++n) {
    const int col = bn + wc * 64 + n * 16 + (lane & 15);
    const int s = col >> 9, h = (col >> 6) & 7, d = col & 63;
    float* dst = (s == 0) ? qb : (s == 1) ? kb : vb;
    const float bv = bias[col];
#pragma unroll
    for (int m = 0; m < 4; ++m) {
      const int row = bm + wr * 64 + m * 16 + (lane >> 4) * 4;
      const int b = row >> 11, t = row & (T - 1);
      float* base = dst + ((size_t)(b * H + h) * T + t) * Dh + d;
#pragma unroll
      for (int r = 0; r < 4; ++r)
        base[(size_t)r * Dh] = acc[m][n][r] + bv;
    }
  }
}

// ---------------------------------------------------------------------------
// Output GEMM (bf16 MFMA): (BT x KD) @ (KD x C) + bias -> f32 out
// ---------------------------------------------------------------------------
__global__ __launch_bounds__(256) void out_gemm_mfma_kernel(
    const unsigned short* __restrict__ Abf, const unsigned short* __restrict__ Wt,
    const float* __restrict__ bias, float* __restrict__ out) {
  __shared__ unsigned short As[128 * 32];
  __shared__ unsigned short Bs[128 * 32];
  f32x4 acc[4][4] = {};
  const int bm = blockIdx.y * 128, bn = blockIdx.x * 128;
  mfma_mainloop(Abf, Wt, bm, bn, As, Bs, acc);
  const int lane = threadIdx.x & 63, wave = threadIdx.x >> 6;
  const int wr = wave >> 1, wc = wave & 1;
#pragma unroll
  for (int n = 0; n < 4; ++n) {
    const int col = bn + wc * 64 + n * 16 + (lane & 15);
    const float bv = bias[col];
#pragma unroll
    for (int m = 0; m < 4; ++m) {
      const int row = bm + wr * 64 + m * 16 + (lane >> 4) * 4;
#pragma unroll
      for (int r = 0; r < 4; ++r)
        out[(size_t)(row + r) * C + col] = acc[m][n][r] + bv;
    }
  }
}

// ---------------------------------------------------------------------------
// x region means: xavg[b*Nr+n][c] = mean over 16 rows (f32, selection path)
// ---------------------------------------------------------------------------
__global__ __launch_bounds__(256) void x_avg_kernel(
    const float* __restrict__ x, float* __restrict__ xavg) {
  const int blk = blockIdx.x;          // b*Nr + n
  const int c = threadIdx.x;           // cols c and c+256
  const float* xp = x + (size_t)blk * R * C;
  float s0 = 0.f, s1 = 0.f;
#pragma unroll
  for (int r = 0; r < R; ++r) { s0 += xp[r * C + c]; s1 += xp[r * C + c + 256]; }
  xavg[(size_t)blk * C + c] = s0 * 0.0625f;
  xavg[(size_t)blk * C + c + 256] = s1 * 0.0625f;
}

// ---------------------------------------------------------------------------
// q_avg/k_avg GEMM in f32 (selection-critical): (B*Nr x 512) @ W[:, :1024]
// 64x64 tile, scatter into (B,H,Nr,Dh)
// ---------------------------------------------------------------------------
__global__ __launch_bounds__(256) void qkavg_gemm_kernel(
    const float* __restrict__ Xa, const float* __restrict__ W,
    const float* __restrict__ bias,
    float* __restrict__ qavg, float* __restrict__ kavg) {
  __shared__ float As[32][68];
  __shared__ float Bs[32][68];
  const int tid = threadIdx.x;
  const int bm = blockIdx.y * 64;
  const int bn = blockIdx.x * 64;
  const int tm4 = (tid >> 4) << 2;
  const int tn4 = (tid & 15) << 2;
  const int arow = tid >> 3;
  const int acol = (tid & 7) << 2;
  const int brow = tid >> 4;
  const int bcol = (tid & 15) << 2;
  float acc[4][4] = {};
  for (int k0 = 0; k0 < KD; k0 += 32) {
#pragma unroll
    for (int p = 0; p < 2; ++p) {
      const float4 a = *(const float4*)&Xa[(size_t)(bm + arow + 32 * p) * KD + (k0 + acol)];
      As[acol + 0][arow + 32 * p] = a.x;
      As[acol + 1][arow + 32 * p] = a.y;
      As[acol + 2][arow + 32 * p] = a.z;
      As[acol + 3][arow + 32 * p] = a.w;
    }
#pragma unroll
    for (int p = 0; p < 2; ++p) {
      *(float4*)&Bs[brow + 16 * p][bcol] =
          *(const float4*)&W[(size_t)(k0 + brow + 16 * p) * QKV_N + (bn + bcol)];
    }
    __syncthreads();
#pragma unroll
    for (int kk = 0; kk < 32; ++kk) {
      const float4 av = *(const float4*)&As[kk][tm4];
      const float4 bv = *(const float4*)&Bs[kk][tn4];
      const float a[4] = {av.x, av.y, av.z, av.w};
      const float bb[4] = {bv.x, bv.y, bv.z, bv.w};
#pragma unroll
      for (int i = 0; i < 4; ++i)
#pragma unroll
        for (int j = 0; j < 4; ++j) acc[i][j] += a[i] * bb[j];
    }
    __syncthreads();
  }
#pragma unroll
  for (int i = 0; i < 4; ++i) {
    const int m = bm + tm4 + i;
    const int b = m >> 7, n = m & (Nr - 1);
#pragma unroll
    for (int j = 0; j < 4; ++j) {
      const int col = bn + tn4 + j;
      const int half = col >> 9, h = (col >> 6) & 7, d = col & 63;
      float* dst = half ? kavg : qavg;
      dst[(((size_t)b * H + h) * Nr + n) * Dh + d] = acc[i][j] + bias[col];
    }
  }
}

// ---------------------------------------------------------------------------
// Region scores + top-8 (ties: lowest index). One block per (b,h,nq).
// ---------------------------------------------------------------------------
__global__ __launch_bounds__(128) void topk_kernel(
    const float* __restrict__ qavg, const float* __restrict__ kavg,
    int* __restrict__ topk) {
  const int blk = blockIdx.x;       // bh*Nr + nq
  const int bh  = blk >> 7;
  const int m   = threadIdx.x;      // key region index
  __shared__ float qrow[Dh];
  __shared__ float sc[Nr];
  __shared__ float rv[Nr];
  __shared__ int   ri[Nr];
  __shared__ int   sel[K];
  if (m < Dh) qrow[m] = qavg[(size_t)blk * Dh + m];
  __syncthreads();
  const float* krow = kavg + ((size_t)bh * Nr + m) * Dh;
  float dot = 0.f;
#pragma unroll
  for (int i = 0; i < Dh; ++i) dot += qrow[i] * krow[i];
  sc[m] = dot;
  bool taken = false;
  __syncthreads();
  for (int j = 0; j < K; ++j) {
    rv[m] = taken ? -INFINITY : sc[m];
    ri[m] = m;
    __syncthreads();
    for (int off = 64; off >= 1; off >>= 1) {
      if (m < off) {
        const float v2 = rv[m + off]; const int i2 = ri[m + off];
        if (v2 > rv[m] || (v2 == rv[m] && i2 < ri[m])) { rv[m] = v2; ri[m] = i2; }
      }
      __syncthreads();
    }
    if (m == 0) sel[j] = ri[0];
    __syncthreads();
    if (m == sel[j]) taken = true;
  }
  if (m < K) topk[blk * K + m] = sel[m];
}

// ---------------------------------------------------------------------------
// Block-sparse attention (f32), writes aout in bf16 for the out GEMM.
// ---------------------------------------------------------------------------
__global__ __launch_bounds__(256) void attn_kernel(
    const float* __restrict__ qb, const float* __restrict__ kb,
    const float* __restrict__ vb, const int* __restrict__ topk,
    unsigned short* __restrict__ aoutbf) {
  const int blk = blockIdx.x;     // bh*Nr + n
  const int bh  = blk >> 7;
  const int n   = blk & (Nr - 1);
  const int b   = bh >> 3;
  const int h   = bh & 7;
  const int tid = threadIdx.x;
  __shared__ float qs[R][68];
  __shared__ float kvs[K * R][68];   // K first, reused for V
  __shared__ float lg[R][K * R];
  __shared__ int ridx[K];
  if (tid < K) ridx[tid] = topk[blk * K + tid];
  {
    const int r = tid >> 4, c4 = (tid & 15) << 2;
    *(float4*)&qs[r][c4] =
        *(const float4*)&qb[((size_t)bh * T + n * R + r) * Dh + c4];
  }
  __syncthreads();
#pragma unroll
  for (int p = 0; p < 8; ++p) {
    const int f = p * 256 + tid;
    const int row = f >> 4, c4 = (f & 15) << 2;
    const int reg = row >> 4, rr = row & 15;
    *(float4*)&kvs[row][c4] =
        *(const float4*)&kb[((size_t)bh * T + ridx[reg] * R + rr) * Dh + c4];
  }
  __syncthreads();
  const int r = tid >> 4;
  const int g = tid & 15;
  float p8[8];
#pragma unroll
  for (int j = 0; j < 8; ++j) {
    const int c = g + 16 * j;
    float dot = 0.f;
#pragma unroll
    for (int i = 0; i < Dh; ++i) dot += qs[r][i] * kvs[c][i];
    p8[j] = dot * SCALE;
  }
  float mx = p8[0];
#pragma unroll
  for (int j = 1; j < 8; ++j) mx = fmaxf(mx, p8[j]);
#pragma unroll
  for (int off = 1; off < 16; off <<= 1) mx = fmaxf(mx, __shfl_xor(mx, off));
  float sum = 0.f;
#pragma unroll
  for (int j = 0; j < 8; ++j) { p8[j] = __expf(p8[j] - mx); sum += p8[j]; }
#pragma unroll
  for (int off = 1; off < 16; off <<= 1) sum += __shfl_xor(sum, off);
  const float inv = 1.f / sum;
#pragma unroll
  for (int j = 0; j < 8; ++j) lg[r][g + 16 * j] = p8[j] * inv;
  __syncthreads();
#pragma unroll
  for (int p = 0; p < 8; ++p) {
    const int f = p * 256 + tid;
    const int row = f >> 4, c4 = (f & 15) << 2;
    const int reg = row >> 4, rr = row & 15;
    *(float4*)&kvs[row][c4] =
        *(const float4*)&vb[((size_t)bh * T + ridx[reg] * R + rr) * Dh + c4];
  }
  __syncthreads();
  const int d0 = g << 2;
  float o0 = 0.f, o1 = 0.f, o2 = 0.f, o3 = 0.f;
#pragma unroll 4
  for (int c = 0; c < K * R; ++c) {
    const float w = lg[r][c];
    const float4 vv = *(const float4*)&kvs[c][d0];
    o0 += w * vv.x; o1 += w * vv.y; o2 += w * vv.z; o3 += w * vv.w;
  }
  ushort4 o;
  o.x = f2bf(o0); o.y = f2bf(o1); o.z = f2bf(o2); o.w = f2bf(o3);
  *(ushort4*)&aoutbf[((size_t)b * T + n * R + r) * C + h * Dh + d0] = o;
}

extern "C" void kernel_launch(void* const* d_in, const int* in_sizes, int n_in,
                              void* d_out, int out_size, void* d_ws, size_t ws_size,
                              hipStream_t stream) {
  const float* x    = (const float*)d_in[0];
  const float* Wqkv = (const float*)d_in[1];
  const float* bqkv = (const float*)d_in[2];
  const float* Wout = (const float*)d_in[3];
  const float* bout = (const float*)d_in[4];
  float* out = (float*)d_out;

  float* ws = (float*)d_ws;
  const size_t bhtd = (size_t)B * H * T * Dh;     // 4,194,304
  const size_t navg = (size_t)B * H * Nr * Dh;    // 262,144
  float* qb   = ws;
  float* kb   = qb + bhtd;
  float* vb   = kb + bhtd;
  float* qavg = vb + bhtd;
  float* kavg = qavg + navg;
  float* xavg = kavg + navg;                       // B*Nr*C = 262,144
  unsigned short* xbf    = (unsigned short*)(xavg + navg);
  unsigned short* wqkvt  = xbf + bhtd;             // 1536*512
  unsigned short* woutt  = wqkvt + (size_t)QKV_N * KD;
  unsigned short* aoutbf = woutt + (size_t)C * KD;
  int* topk = (int*)(aoutbf + bhtd);

  convert_x_kernel<<<4096, 256, 0, stream>>>((const float4*)x, (ushort4*)xbf);
  transpose_convert_kernel<<<dim3(QKV_N / 32, KD / 32), 256, 0, stream>>>(Wqkv, wqkvt, KD, QKV_N);
  transpose_convert_kernel<<<dim3(C / 32, KD / 32), 256, 0, stream>>>(Wout, woutt, KD, C);
  x_avg_kernel<<<B * Nr, 256, 0, stream>>>(x, xavg);
  qkavg_gemm_kernel<<<dim3(1024 / 64, (B * Nr) / 64), 256, 0, stream>>>(xavg, Wqkv, bqkv, qavg, kavg);
  topk_kernel<<<B * H * Nr, 128, 0, stream>>>(qavg, kavg, topk);
  qkv_gemm_mfma_kernel<<<dim3(QKV_N / 128, BT / 128), 256, 0, stream>>>(xbf, wqkvt, bqkv, qb, kb, vb);
  attn_kernel<<<B * H * Nr, 256, 0, stream>>>(qb, kb, vb, topk, aoutbf);
  out_gemm_mfma_kernel<<<dim3(C / 128, BT / 128), 256, 0, stream>>>(aoutbf, woutt, bout, out);
}

// Round 3
// 137.320 us; speedup vs baseline: 2.4169x; 1.2196x over previous
//
#include <hip/hip_runtime.h>
#include <hip/hip_bf16.h>
#include <math.h>

typedef __bf16 bf16x8 __attribute__((ext_vector_type(8)));
typedef float f32x4 __attribute__((ext_vector_type(4)));

namespace {
constexpr int B  = 4;
constexpr int T  = 2048;
constexpr int C  = 512;
constexpr int H  = 8;
constexpr int Dh = 64;
constexpr int R  = 16;
constexpr int Nr = 128;   // T / R
constexpr int K  = 8;     // top-k regions
constexpr int BT = B * T;        // 8192
constexpr int QKV_N = 3 * C;     // 1536
constexpr int KD = 512;          // GEMM inner depth (= C)
constexpr float SCALE = 0.125f;  // 1/sqrt(Dh)
}

static __device__ __forceinline__ unsigned short f2bf(float f) {
  unsigned int u = __float_as_uint(f);
  u += 0x7fffu + ((u >> 16) & 1u);   // RNE
  return (unsigned short)(u >> 16);
}

static __device__ __forceinline__ unsigned cvt_pk_bf16(float lo, float hi) {
  unsigned r;
  asm("v_cvt_pk_bf16_f32 %0, %1, %2" : "=v"(r) : "v"(lo), "v"(hi));
  return r;
}

static __device__ __forceinline__ void gload16(const unsigned short* g, unsigned short* l) {
  __builtin_amdgcn_global_load_lds(
      (const __attribute__((address_space(1))) unsigned int*)g,
      (__attribute__((address_space(3))) unsigned int*)l, 16, 0, 0);
}

// ---------------------------------------------------------------------------
// x (f32) -> xbf (bf16), elementwise
// ---------------------------------------------------------------------------
__global__ __launch_bounds__(256) void convert_x_kernel(
    const float4* __restrict__ x, ushort4* __restrict__ xbf) {
  const int i = blockIdx.x * 256 + threadIdx.x;
  const float4 v = x[i];
  ushort4 o;
  o.x = f2bf(v.x); o.y = f2bf(v.y); o.z = f2bf(v.z); o.w = f2bf(v.w);
  xbf[i] = o;
}

// ---------------------------------------------------------------------------
// W (Kd x Nd f32, row-major) -> Wt (Nd x Kd bf16)  [transpose + convert]
// ---------------------------------------------------------------------------
__global__ __launch_bounds__(256) void transpose_convert_kernel(
    const float* __restrict__ W, unsigned short* __restrict__ Wt, int Kd, int Nd) {
  __shared__ float tile[32][33];
  const int n0 = blockIdx.x * 32, k0 = blockIdx.y * 32;
  const int tx = threadIdx.x & 31, ty = threadIdx.x >> 5;   // ty 0..7
#pragma unroll
  for (int i = 0; i < 32; i += 8)
    tile[ty + i][tx] = W[(size_t)(k0 + ty + i) * Nd + (n0 + tx)];
  __syncthreads();
#pragma unroll
  for (int i = 0; i < 32; i += 8)
    Wt[(size_t)(n0 + ty + i) * Kd + (k0 + tx)] = f2bf(tile[tx][ty + i]);
}

// ---------------------------------------------------------------------------
// Shared bf16-MFMA mainloop: 128x128 tile, BK=32, 4 waves, each wave 64x64.
// ---------------------------------------------------------------------------
__device__ __forceinline__ void mfma_mainloop(
    const unsigned short* __restrict__ A, const unsigned short* __restrict__ Bt,
    int bm, int bn, unsigned short* As, unsigned short* Bs, f32x4 (&acc)[4][4]) {
  const int tid = threadIdx.x;
  const int wave = tid >> 6, lane = tid & 63;
  const int wr = wave >> 1, wc = wave & 1;
  const unsigned short* ga = A  + (size_t)(bm + wave * 16 + (lane >> 2)) * KD + (lane & 3) * 8;
  const unsigned short* gb = Bt + (size_t)(bn + wave * 16 + (lane >> 2)) * KD + (lane & 3) * 8;
  unsigned short* lA = As + wave * 512;
  unsigned short* lB = Bs + wave * 512;
  const int fr = lane & 15, kg = lane >> 4;
  const unsigned short* rA = As + (wr * 64 + fr) * 32 + kg * 8;
  const unsigned short* rB = Bs + (wc * 64 + fr) * 32 + kg * 8;
  for (int k0 = 0; k0 < KD; k0 += 32) {
    gload16(ga + k0,                    lA);
    gload16(ga + (size_t)64 * KD + k0,  lA + 2048);
    gload16(gb + k0,                    lB);
    gload16(gb + (size_t)64 * KD + k0,  lB + 2048);
    __syncthreads();
    bf16x8 a[4], b[4];
#pragma unroll
    for (int m = 0; m < 4; ++m) a[m] = *(const bf16x8*)(rA + m * 512);
#pragma unroll
    for (int n = 0; n < 4; ++n) b[n] = *(const bf16x8*)(rB + n * 512);
#pragma unroll
    for (int m = 0; m < 4; ++m)
#pragma unroll
      for (int n = 0; n < 4; ++n)
        acc[m][n] = __builtin_amdgcn_mfma_f32_16x16x32_bf16(a[m], b[n], acc[m][n], 0, 0, 0);
    __syncthreads();
  }
}

// ---------------------------------------------------------------------------
// QKV GEMM (bf16 MFMA): writes q,k as bf16 [bh][t][d]; v as bf16 [bh][d][t]
// ---------------------------------------------------------------------------
__global__ __launch_bounds__(256) void qkv_gemm_mfma_kernel(
    const unsigned short* __restrict__ xbf, const unsigned short* __restrict__ Wt,
    const float* __restrict__ bias,
    unsigned short* __restrict__ qbf, unsigned short* __restrict__ kbf,
    unsigned short* __restrict__ vt) {
  __shared__ unsigned short As[128 * 32];
  __shared__ unsigned short Bs[128 * 32];
  f32x4 acc[4][4] = {};
  const int bm = blockIdx.y * 128, bn = blockIdx.x * 128;
  mfma_mainloop(xbf, Wt, bm, bn, As, Bs, acc);
  const int lane = threadIdx.x & 63, wave = threadIdx.x >> 6;
  const int wr = wave >> 1, wc = wave & 1;
#pragma unroll
  for (int n = 0; n < 4; ++n) {
    const int col = bn + wc * 64 + n * 16 + (lane & 15);
    const int s = col >> 9, h = (col >> 6) & 7, d = col & 63;
    const float bv = bias[col];
#pragma unroll
    for (int m = 0; m < 4; ++m) {
      const int row = bm + wr * 64 + m * 16 + (lane >> 4) * 4;
      const int b = row >> 11, t = row & (T - 1);
      const int bh = b * H + h;
      if (s == 2) {
        ushort4 pk;
        pk.x = f2bf(acc[m][n][0] + bv); pk.y = f2bf(acc[m][n][1] + bv);
        pk.z = f2bf(acc[m][n][2] + bv); pk.w = f2bf(acc[m][n][3] + bv);
        *(ushort4*)&vt[((size_t)bh * Dh + d) * T + t] = pk;
      } else {
        unsigned short* dst = ((s == 0) ? qbf : kbf) + ((size_t)bh * T + t) * Dh + d;
#pragma unroll
        for (int r = 0; r < 4; ++r) dst[(size_t)r * Dh] = f2bf(acc[m][n][r] + bv);
      }
    }
  }
}

// ---------------------------------------------------------------------------
// Output GEMM (bf16 MFMA): (BT x KD) @ (KD x C) + bias -> f32 out
// ---------------------------------------------------------------------------
__global__ __launch_bounds__(256) void out_gemm_mfma_kernel(
    const unsigned short* __restrict__ Abf, const unsigned short* __restrict__ Wt,
    const float* __restrict__ bias, float* __restrict__ out) {
  __shared__ unsigned short As[128 * 32];
  __shared__ unsigned short Bs[128 * 32];
  f32x4 acc[4][4] = {};
  const int bm = blockIdx.y * 128, bn = blockIdx.x * 128;
  mfma_mainloop(Abf, Wt, bm, bn, As, Bs, acc);
  const int lane = threadIdx.x & 63, wave = threadIdx.x >> 6;
  const int wr = wave >> 1, wc = wave & 1;
#pragma unroll
  for (int n = 0; n < 4; ++n) {
    const int col = bn + wc * 64 + n * 16 + (lane & 15);
    const float bv = bias[col];
#pragma unroll
    for (int m = 0; m < 4; ++m) {
      const int row = bm + wr * 64 + m * 16 + (lane >> 4) * 4;
#pragma unroll
      for (int r = 0; r < 4; ++r)
        out[(size_t)(row + r) * C + col] = acc[m][n][r] + bv;
    }
  }
}

// ---------------------------------------------------------------------------
// x region means (f32, selection path)
// ---------------------------------------------------------------------------
__global__ __launch_bounds__(256) void x_avg_kernel(
    const float* __restrict__ x, float* __restrict__ xavg) {
  const int blk = blockIdx.x;          // b*Nr + n
  const int c = threadIdx.x;
  const float* xp = x + (size_t)blk * R * C;
  float s0 = 0.f, s1 = 0.f;
#pragma unroll
  for (int r = 0; r < R; ++r) { s0 += xp[r * C + c]; s1 += xp[r * C + c + 256]; }
  xavg[(size_t)blk * C + c] = s0 * 0.0625f;
  xavg[(size_t)blk * C + c + 256] = s1 * 0.0625f;
}

// ---------------------------------------------------------------------------
// q_avg/k_avg GEMM in f32 (selection-critical)
// ---------------------------------------------------------------------------
__global__ __launch_bounds__(256) void qkavg_gemm_kernel(
    const float* __restrict__ Xa, const float* __restrict__ W,
    const float* __restrict__ bias,
    float* __restrict__ qavg, float* __restrict__ kavg) {
  __shared__ float As[32][68];
  __shared__ float Bs[32][68];
  const int tid = threadIdx.x;
  const int bm = blockIdx.y * 64;
  const int bn = blockIdx.x * 64;
  const int tm4 = (tid >> 4) << 2;
  const int tn4 = (tid & 15) << 2;
  const int arow = tid >> 3;
  const int acol = (tid & 7) << 2;
  const int brow = tid >> 4;
  const int bcol = (tid & 15) << 2;
  float acc[4][4] = {};
  for (int k0 = 0; k0 < KD; k0 += 32) {
#pragma unroll
    for (int p = 0; p < 2; ++p) {
      const float4 a = *(const float4*)&Xa[(size_t)(bm + arow + 32 * p) * KD + (k0 + acol)];
      As[acol + 0][arow + 32 * p] = a.x;
      As[acol + 1][arow + 32 * p] = a.y;
      As[acol + 2][arow + 32 * p] = a.z;
      As[acol + 3][arow + 32 * p] = a.w;
    }
#pragma unroll
    for (int p = 0; p < 2; ++p) {
      *(float4*)&Bs[brow + 16 * p][bcol] =
          *(const float4*)&W[(size_t)(k0 + brow + 16 * p) * QKV_N + (bn + bcol)];
    }
    __syncthreads();
#pragma unroll
    for (int kk = 0; kk < 32; ++kk) {
      const float4 av = *(const float4*)&As[kk][tm4];
      const float4 bv = *(const float4*)&Bs[kk][tn4];
      const float a[4] = {av.x, av.y, av.z, av.w};
      const float bb[4] = {bv.x, bv.y, bv.z, bv.w};
#pragma unroll
      for (int i = 0; i < 4; ++i)
#pragma unroll
        for (int j = 0; j < 4; ++j) acc[i][j] += a[i] * bb[j];
    }
    __syncthreads();
  }
#pragma unroll
  for (int i = 0; i < 4; ++i) {
    const int m = bm + tm4 + i;
    const int b = m >> 7, n = m & (Nr - 1);
#pragma unroll
    for (int j = 0; j < 4; ++j) {
      const int col = bn + tn4 + j;
      const int half = col >> 9, h = (col >> 6) & 7, d = col & 63;
      float* dst = half ? kavg : qavg;
      dst[(((size_t)b * H + h) * Nr + n) * Dh + d] = acc[i][j] + bias[col];
    }
  }
}

// ---------------------------------------------------------------------------
// Region scores + top-8 (ties: lowest index). One block per (b,h,nq).
// ---------------------------------------------------------------------------
__global__ __launch_bounds__(128) void topk_kernel(
    const float* __restrict__ qavg, const float* __restrict__ kavg,
    int* __restrict__ topk) {
  const int blk = blockIdx.x;
  const int bh  = blk >> 7;
  const int m   = threadIdx.x;
  __shared__ float qrow[Dh];
  __shared__ float sc[Nr];
  __shared__ float rv[Nr];
  __shared__ int   ri[Nr];
  __shared__ int   sel[K];
  if (m < Dh) qrow[m] = qavg[(size_t)blk * Dh + m];
  __syncthreads();
  const float* krow = kavg + ((size_t)bh * Nr + m) * Dh;
  float dot = 0.f;
#pragma unroll
  for (int i = 0; i < Dh; ++i) dot += qrow[i] * krow[i];
  sc[m] = dot;
  bool taken = false;
  __syncthreads();
  for (int j = 0; j < K; ++j) {
    rv[m] = taken ? -INFINITY : sc[m];
    ri[m] = m;
    __syncthreads();
    for (int off = 64; off >= 1; off >>= 1) {
      if (m < off) {
        const float v2 = rv[m + off]; const int i2 = ri[m + off];
        if (v2 > rv[m] || (v2 == rv[m] && i2 < ri[m])) { rv[m] = v2; ri[m] = i2; }
      }
      __syncthreads();
    }
    if (m == 0) sel[j] = ri[0];
    __syncthreads();
    if (m == sel[j]) taken = true;
  }
  if (m < K) topk[blk * K + m] = sel[m];
}

// ---------------------------------------------------------------------------
// MFMA block-sparse attention: 1 wave per (bh, n). No LDS.
// S^T tiles = mfma(K_rows, Q); softmax in-register (col=q is lane-local);
// PV as out^T = V^T * P^T with V^T frags from global vt, P^T via cvt_pk+shfl.
// ---------------------------------------------------------------------------
__global__ __launch_bounds__(64) void attn_mfma_kernel(
    const unsigned short* __restrict__ qbf, const unsigned short* __restrict__ kbf,
    const unsigned short* __restrict__ vt, const int* __restrict__ topk,
    unsigned short* __restrict__ aoutbf) {
  // XCD-chunked swizzle: 4096 blocks, 8 XCDs, 512 per XCD
  const int phys = blockIdx.x;
  const int blk = (phys & 7) * 512 + (phys >> 3);
  const int bh = blk >> 7, n = blk & (Nr - 1);
  const int b = bh >> 3, h = bh & 7;
  const int lane = threadIdx.x;
  const int q = lane & 15, kg = lane >> 4;
  const int kg1 = kg & 1, kgh = kg >> 1;

  const int rv = topk[blk * K + (lane & 7)];
  int ridx[8];
#pragma unroll
  for (int j = 0; j < 8; ++j) ridx[j] = __shfl(rv, j);

  // Q fragments (B operand): lane reads Q[q][kg*8 + 32t + 0..7]
  const unsigned short* qp = qbf + ((size_t)bh * T + n * R + q) * Dh + kg * 8;
  const bf16x8 qf0 = *(const bf16x8*)(qp);
  const bf16x8 qf1 = *(const bf16x8*)(qp + 32);

  // QK^T: 8 S^T tiles (16 sel-rows x 16 q)
  f32x4 s[8];
#pragma unroll
  for (int j = 0; j < 8; ++j) {
    const unsigned short* kp = kbf + ((size_t)bh * T + ridx[j] * R + q) * Dh + kg * 8;
    const bf16x8 kf0 = *(const bf16x8*)(kp);
    const bf16x8 kf1 = *(const bf16x8*)(kp + 32);
    f32x4 acc = {};
    acc = __builtin_amdgcn_mfma_f32_16x16x32_bf16(kf0, qf0, acc, 0, 0, 0);
    acc = __builtin_amdgcn_mfma_f32_16x16x32_bf16(kf1, qf1, acc, 0, 0, 0);
    s[j] = acc;
  }

  // softmax over all 128 k for fixed q (lanes kg=0..3 share q)
  float mx = s[0][0];
#pragma unroll
  for (int j = 0; j < 8; ++j)
#pragma unroll
    for (int r = 0; r < 4; ++r) mx = fmaxf(mx, s[j][r]);
  mx = fmaxf(mx, __shfl_xor(mx, 16));
  mx = fmaxf(mx, __shfl_xor(mx, 32));
  float sum = 0.f;
#pragma unroll
  for (int j = 0; j < 8; ++j)
#pragma unroll
    for (int r = 0; r < 4; ++r) {
      const float e = __expf((s[j][r] - mx) * SCALE);
      s[j][r] = e; sum += e;
    }
  sum += __shfl_xor(sum, 16);
  sum += __shfl_xor(sum, 32);

  // pack P rows to bf16 pairs: pk0[j] = rows(kg*4+0,+1), pk1[j] = rows(+2,+3)
  unsigned pk0[8], pk1[8];
#pragma unroll
  for (int j = 0; j < 8; ++j) {
    pk0[j] = cvt_pk_bf16(s[j][0], s[j][1]);
    pk1[j] = cvt_pk_bf16(s[j][2], s[j][3]);
  }

  // PV: out^T tiles dt (16 d x 16 q), k-steps t (32 gathered rows each)
  const int srcA = kg1 * 32 + q;        // lanes kg_src = kg1*2
  const int srcB = kg1 * 32 + 16 + q;   // kg_src = kg1*2 + 1
  f32x4 o[4] = {};
#pragma unroll
  for (int t = 0; t < 4; ++t) {
    // B-frag (P^T): lane needs k = 32t + kg*8 + 0..7 for its q
    const unsigned aa0 = __shfl((int)pk0[2 * t], srcA), aa1 = __shfl((int)pk0[2 * t + 1], srcA);
    const unsigned ab0 = __shfl((int)pk1[2 * t], srcA), ab1 = __shfl((int)pk1[2 * t + 1], srcA);
    const unsigned ba0 = __shfl((int)pk0[2 * t], srcB), ba1 = __shfl((int)pk0[2 * t + 1], srcB);
    const unsigned bb0 = __shfl((int)pk1[2 * t], srcB), bb1 = __shfl((int)pk1[2 * t + 1], srcB);
    union { uint4 u; bf16x8 v; } bu;
    bu.u.x = kgh ? aa1 : aa0;
    bu.u.y = kgh ? ab1 : ab0;
    bu.u.z = kgh ? ba1 : ba0;
    bu.u.w = kgh ? bb1 : bb0;
    // region for my k-slice and token base
    const int reg = kgh ? ridx[2 * t + 1] : ridx[2 * t];
    const size_t tok = (size_t)reg * R + kg1 * 8;
#pragma unroll
    for (int dt = 0; dt < 4; ++dt) {
      const bf16x8 af = *(const bf16x8*)(vt + ((size_t)bh * Dh + 16 * dt + q) * T + tok);
      o[dt] = __builtin_amdgcn_mfma_f32_16x16x32_bf16(af, bu.v, o[dt], 0, 0, 0);
    }
  }

  // epilogue: out[q_row=q][d = 16dt + kg*4 + r], deferred normalization
  const float inv = 1.0f / sum;
  unsigned short* dst = aoutbf + ((size_t)b * T + n * R + q) * C + h * Dh;
#pragma unroll
  for (int dt = 0; dt < 4; ++dt) {
    const unsigned plo = cvt_pk_bf16(o[dt][0] * inv, o[dt][1] * inv);
    const unsigned phi = cvt_pk_bf16(o[dt][2] * inv, o[dt][3] * inv);
    uint2 st; st.x = plo; st.y = phi;
    *(uint2*)(dst + 16 * dt + kg * 4) = st;
  }
}

extern "C" void kernel_launch(void* const* d_in, const int* in_sizes, int n_in,
                              void* d_out, int out_size, void* d_ws, size_t ws_size,
                              hipStream_t stream) {
  const float* x    = (const float*)d_in[0];
  const float* Wqkv = (const float*)d_in[1];
  const float* bqkv = (const float*)d_in[2];
  const float* Wout = (const float*)d_in[3];
  const float* bout = (const float*)d_in[4];
  float* out = (float*)d_out;

  float* ws = (float*)d_ws;
  const size_t bhtd = (size_t)B * H * T * Dh;     // 4,194,304
  const size_t navg = (size_t)B * H * Nr * Dh;    // 262,144
  float* qavg = ws;
  float* kavg = qavg + navg;
  float* xavg = kavg + navg;                       // B*Nr*C
  unsigned short* qbf    = (unsigned short*)(xavg + navg);
  unsigned short* kbf    = qbf + bhtd;
  unsigned short* vt     = kbf + bhtd;
  unsigned short* xbf    = vt + bhtd;
  unsigned short* wqkvt  = xbf + bhtd;
  unsigned short* woutt  = wqkvt + (size_t)QKV_N * KD;
  unsigned short* aoutbf = woutt + (size_t)C * KD;
  int* topk = (int*)(aoutbf + bhtd);

  convert_x_kernel<<<4096, 256, 0, stream>>>((const float4*)x, (ushort4*)xbf);
  transpose_convert_kernel<<<dim3(QKV_N / 32, KD / 32), 256, 0, stream>>>(Wqkv, wqkvt, KD, QKV_N);
  transpose_convert_kernel<<<dim3(C / 32, KD / 32), 256, 0, stream>>>(Wout, woutt, KD, C);
  x_avg_kernel<<<B * Nr, 256, 0, stream>>>(x, xavg);
  qkavg_gemm_kernel<<<dim3(1024 / 64, (B * Nr) / 64), 256, 0, stream>>>(xavg, Wqkv, bqkv, qavg, kavg);
  topk_kernel<<<B * H * Nr, 128, 0, stream>>>(qavg, kavg, topk);
  qkv_gemm_mfma_kernel<<<dim3(QKV_N / 128, BT / 128), 256, 0, stream>>>(xbf, wqkvt, bqkv, qbf, kbf, vt);
  attn_mfma_kernel<<<B * H * Nr, 64, 0, stream>>>(qbf, kbf, vt, topk, aoutbf);
  out_gemm_mfma_kernel<<<dim3(C / 128, BT / 128), 256, 0, stream>>>(aoutbf, woutt, bout, out);
}

// Round 4
// 132.443 us; speedup vs baseline: 2.5059x; 1.0368x over previous
//
#include <hip/hip_runtime.h>
#include <hip/hip_bf16.h>
#include <math.h>

typedef __bf16 bf16x8 __attribute__((ext_vector_type(8)));
typedef float f32x4 __attribute__((ext_vector_type(4)));

namespace {
constexpr int B  = 4;
constexpr int T  = 2048;
constexpr int C  = 512;
constexpr int H  = 8;
constexpr int Dh = 64;
constexpr int R  = 16;
constexpr int Nr = 128;   // T / R
constexpr int K  = 8;     // top-k regions
constexpr int BT = B * T;        // 8192
constexpr int QKV_N = 3 * C;     // 1536
constexpr int KD = 512;          // GEMM inner depth (= C)
constexpr float SCALE = 0.125f;  // 1/sqrt(Dh)
}

static __device__ __forceinline__ unsigned short f2bf(float f) {
  unsigned int u = __float_as_uint(f);
  u += 0x7fffu + ((u >> 16) & 1u);   // RNE
  return (unsigned short)(u >> 16);
}

static __device__ __forceinline__ unsigned cvt_pk_bf16(float lo, float hi) {
  unsigned r;
  asm("v_cvt_pk_bf16_f32 %0, %1, %2" : "=v"(r) : "v"(lo), "v"(hi));
  return r;
}

static __device__ __forceinline__ void gload16(const unsigned short* g, unsigned short* l) {
  __builtin_amdgcn_global_load_lds(
      (const __attribute__((address_space(1))) unsigned int*)g,
      (__attribute__((address_space(3))) unsigned int*)l, 16, 0, 0);
}

// order-preserving f32 -> u32 key (max-compatible, no NaN expected)
static __device__ __forceinline__ unsigned fkey(float f) {
  unsigned u = __float_as_uint(f);
  return (u & 0x80000000u) ? ~u : (u ^ 0x80000000u);
}

// ---------------------------------------------------------------------------
// x (f32) -> xbf (bf16), elementwise
// ---------------------------------------------------------------------------
__global__ __launch_bounds__(256) void convert_x_kernel(
    const float4* __restrict__ x, ushort4* __restrict__ xbf) {
  const int i = blockIdx.x * 256 + threadIdx.x;
  const float4 v = x[i];
  ushort4 o;
  o.x = f2bf(v.x); o.y = f2bf(v.y); o.z = f2bf(v.z); o.w = f2bf(v.w);
  xbf[i] = o;
}

// ---------------------------------------------------------------------------
// W (Kd x Nd f32, row-major) -> Wt (Nd x Kd bf16)  [transpose + convert]
// ---------------------------------------------------------------------------
__global__ __launch_bounds__(256) void transpose_convert_kernel(
    const float* __restrict__ W, unsigned short* __restrict__ Wt, int Kd, int Nd) {
  __shared__ float tile[32][33];
  const int n0 = blockIdx.x * 32, k0 = blockIdx.y * 32;
  const int tx = threadIdx.x & 31, ty = threadIdx.x >> 5;   // ty 0..7
#pragma unroll
  for (int i = 0; i < 32; i += 8)
    tile[ty + i][tx] = W[(size_t)(k0 + ty + i) * Nd + (n0 + tx)];
  __syncthreads();
#pragma unroll
  for (int i = 0; i < 32; i += 8)
    Wt[(size_t)(n0 + ty + i) * Kd + (k0 + tx)] = f2bf(tile[tx][ty + i]);
}

// ---------------------------------------------------------------------------
// Shared bf16-MFMA mainloop: 128x128 tile, BK=32, 4 waves, each wave 64x64.
// ---------------------------------------------------------------------------
__device__ __forceinline__ void mfma_mainloop(
    const unsigned short* __restrict__ A, const unsigned short* __restrict__ Bt,
    int bm, int bn, unsigned short* As, unsigned short* Bs, f32x4 (&acc)[4][4]) {
  const int tid = threadIdx.x;
  const int wave = tid >> 6, lane = tid & 63;
  const int wr = wave >> 1, wc = wave & 1;
  const unsigned short* ga = A  + (size_t)(bm + wave * 16 + (lane >> 2)) * KD + (lane & 3) * 8;
  const unsigned short* gb = Bt + (size_t)(bn + wave * 16 + (lane >> 2)) * KD + (lane & 3) * 8;
  unsigned short* lA = As + wave * 512;
  unsigned short* lB = Bs + wave * 512;
  const int fr = lane & 15, kg = lane >> 4;
  const unsigned short* rA = As + (wr * 64 + fr) * 32 + kg * 8;
  const unsigned short* rB = Bs + (wc * 64 + fr) * 32 + kg * 8;
  for (int k0 = 0; k0 < KD; k0 += 32) {
    gload16(ga + k0,                    lA);
    gload16(ga + (size_t)64 * KD + k0,  lA + 2048);
    gload16(gb + k0,                    lB);
    gload16(gb + (size_t)64 * KD + k0,  lB + 2048);
    __syncthreads();
    bf16x8 a[4], b[4];
#pragma unroll
    for (int m = 0; m < 4; ++m) a[m] = *(const bf16x8*)(rA + m * 512);
#pragma unroll
    for (int n = 0; n < 4; ++n) b[n] = *(const bf16x8*)(rB + n * 512);
#pragma unroll
    for (int m = 0; m < 4; ++m)
#pragma unroll
      for (int n = 0; n < 4; ++n)
        acc[m][n] = __builtin_amdgcn_mfma_f32_16x16x32_bf16(a[m], b[n], acc[m][n], 0, 0, 0);
    __syncthreads();
  }
}

// ---------------------------------------------------------------------------
// QKV GEMM (bf16 MFMA): q,k bf16 [bh][t][d] via in-wave 4x4 transpose (uint2
// stores); v bf16 [bh][d][t]. XCD-chunked block swizzle.
// ---------------------------------------------------------------------------
__global__ __launch_bounds__(256) void qkv_gemm_mfma_kernel(
    const unsigned short* __restrict__ xbf, const unsigned short* __restrict__ Wt,
    const float* __restrict__ bias,
    unsigned short* __restrict__ qbf, unsigned short* __restrict__ kbf,
    unsigned short* __restrict__ vt) {
  __shared__ unsigned short As[128 * 32];
  __shared__ unsigned short Bs[128 * 32];
  f32x4 acc[4][4] = {};
  // grid = 768 = 12 x 64; chunked XCD swizzle (768 % 8 == 0 -> bijective)
  const int id = (blockIdx.x & 7) * 96 + (blockIdx.x >> 3);
  const int bn = (id % 12) * 128, bm = (id / 12) * 128;
  mfma_mainloop(xbf, Wt, bm, bn, As, Bs, acc);
  const int lane = threadIdx.x & 63, wave = threadIdx.x >> 6;
  const int wr = wave >> 1, wc = wave & 1;
  const int scol = bn + wc * 64;           // 64-aligned -> s,h uniform per wave
  const int s = scol >> 9, h = (scol >> 6) & 7;
  const int b = bm >> 11, t0b = (bm & (T - 1)) + wr * 64;
  const int bh = b * H + h;
  if (s == 2) {
    // V: [bh][d][t], lane holds 4 consecutive t at fixed d -> ushort4
#pragma unroll
    for (int n = 0; n < 4; ++n) {
      const int d = (n * 16 + (lane & 15));
      const float bv = bias[scol + n * 16 + (lane & 15)];
#pragma unroll
      for (int m = 0; m < 4; ++m) {
        const int t = t0b + m * 16 + (lane >> 4) * 4;
        ushort4 pk;
        pk.x = f2bf(acc[m][n][0] + bv); pk.y = f2bf(acc[m][n][1] + bv);
        pk.z = f2bf(acc[m][n][2] + bv); pk.w = f2bf(acc[m][n][3] + bv);
        *(ushort4*)&vt[((size_t)bh * Dh + d) * T + t] = pk;
      }
    }
  } else {
    // Q/K: [bh][t][d] via in-wave 4x4 transpose within lane groups {16g+4a+i}
    unsigned short* dstbase = ((s == 0) ? qbf : kbf) + (size_t)bh * T * Dh;
    const int g = lane >> 4, i = lane & 3, a = (lane >> 2) & 3;
#pragma unroll
    for (int n = 0; n < 4; ++n) {
      const float bv = bias[scol + n * 16 + (lane & 15)];
#pragma unroll
      for (int m = 0; m < 4; ++m) {
        const float v0 = acc[m][n][0] + bv, v1 = acc[m][n][1] + bv;
        const float v2 = acc[m][n][2] + bv, v3 = acc[m][n][3] + bv;
        const unsigned p01 = cvt_pk_bf16(v0, v1);
        const unsigned p23 = cvt_pk_bf16(v2, v3);
        const unsigned u01 = (unsigned)__shfl_xor((int)p01, 1);
        const unsigned u23 = (unsigned)__shfl_xor((int)p23, 1);
        const unsigned A  = (lane & 1) ? ((u01 >> 16) | (p01 & 0xFFFF0000u))
                                       : ((p01 & 0xFFFFu) | (u01 << 16));
        const unsigned Bb = (lane & 1) ? ((u23 >> 16) | (p23 & 0xFFFF0000u))
                                       : ((p23 & 0xFFFFu) | (u23 << 16));
        const unsigned w  = (unsigned)__shfl_xor((int)A, 2);
        const unsigned xw = (unsigned)__shfl_xor((int)Bb, 2);
        uint2 res;
        res.x = (lane & 2) ? xw : A;
        res.y = (lane & 2) ? Bb : w;
        const int t = t0b + m * 16 + 4 * g + i;
        const int d = n * 16 + 4 * a;
        *(uint2*)&dstbase[(size_t)t * Dh + d] = res;
      }
    }
  }
}

// ---------------------------------------------------------------------------
// Output GEMM (bf16 MFMA): (BT x KD) @ (KD x C) + bias -> f32 out
// ---------------------------------------------------------------------------
__global__ __launch_bounds__(256) void out_gemm_mfma_kernel(
    const unsigned short* __restrict__ Abf, const unsigned short* __restrict__ Wt,
    const float* __restrict__ bias, float* __restrict__ out) {
  __shared__ unsigned short As[128 * 32];
  __shared__ unsigned short Bs[128 * 32];
  f32x4 acc[4][4] = {};
  // grid = 256 = 4 x 64; chunked XCD swizzle
  const int id = (blockIdx.x & 7) * 32 + (blockIdx.x >> 3);
  const int bn = (id & 3) * 128, bm = (id >> 2) * 128;
  mfma_mainloop(Abf, Wt, bm, bn, As, Bs, acc);
  const int lane = threadIdx.x & 63, wave = threadIdx.x >> 6;
  const int wr = wave >> 1, wc = wave & 1;
#pragma unroll
  for (int n = 0; n < 4; ++n) {
    const int col = bn + wc * 64 + n * 16 + (lane & 15);
    const float bv = bias[col];
#pragma unroll
    for (int m = 0; m < 4; ++m) {
      const int row = bm + wr * 64 + m * 16 + (lane >> 4) * 4;
#pragma unroll
      for (int r = 0; r < 4; ++r)
        out[(size_t)(row + r) * C + col] = acc[m][n][r] + bv;
    }
  }
}

// ---------------------------------------------------------------------------
// x region means (f32, selection path)
// ---------------------------------------------------------------------------
__global__ __launch_bounds__(256) void x_avg_kernel(
    const float* __restrict__ x, float* __restrict__ xavg) {
  const int blk = blockIdx.x;          // b*Nr + n
  const int c = threadIdx.x;
  const float* xp = x + (size_t)blk * R * C;
  float s0 = 0.f, s1 = 0.f;
#pragma unroll
  for (int r = 0; r < R; ++r) { s0 += xp[r * C + c]; s1 += xp[r * C + c + 256]; }
  xavg[(size_t)blk * C + c] = s0 * 0.0625f;
  xavg[(size_t)blk * C + c + 256] = s1 * 0.0625f;
}

// ---------------------------------------------------------------------------
// q_avg/k_avg GEMM in f32 (selection-critical). 512 threads, 4x2 microtile.
// Same accumulation order as before (bit-exact selection).
// ---------------------------------------------------------------------------
__global__ __launch_bounds__(512) void qkavg_gemm_kernel(
    const float* __restrict__ Xa, const float* __restrict__ W,
    const float* __restrict__ bias,
    float* __restrict__ qavg, float* __restrict__ kavg) {
  __shared__ float As[32][68];
  __shared__ float Bs[32][68];
  const int tid = threadIdx.x;
  const int bm = blockIdx.y * 64;
  const int bn = blockIdx.x * 64;
  const int tm = (tid >> 5) << 2;       // 0..60
  const int tn = (tid & 31) << 1;       // 0..62
  const int arow = tid >> 3;            // 0..63
  const int acol = (tid & 7) << 2;      // 0..28
  const int brow = tid >> 4;            // 0..31
  const int bcol = (tid & 15) << 2;     // 0..60
  float acc[4][2] = {};
  for (int k0 = 0; k0 < KD; k0 += 32) {
    {
      const float4 a = *(const float4*)&Xa[(size_t)(bm + arow) * KD + (k0 + acol)];
      As[acol + 0][arow] = a.x;
      As[acol + 1][arow] = a.y;
      As[acol + 2][arow] = a.z;
      As[acol + 3][arow] = a.w;
      *(float4*)&Bs[brow][bcol] =
          *(const float4*)&W[(size_t)(k0 + brow) * QKV_N + (bn + bcol)];
    }
    __syncthreads();
#pragma unroll
    for (int kk = 0; kk < 32; ++kk) {
      const float4 av = *(const float4*)&As[kk][tm];
      const float2 bv = *(const float2*)&Bs[kk][tn];
      const float aa[4] = {av.x, av.y, av.z, av.w};
#pragma unroll
      for (int i = 0; i < 4; ++i) {
        acc[i][0] += aa[i] * bv.x;
        acc[i][1] += aa[i] * bv.y;
      }
    }
    __syncthreads();
  }
#pragma unroll
  for (int i = 0; i < 4; ++i) {
    const int m = bm + tm + i;
    const int b = m >> 7, n = m & (Nr - 1);
#pragma unroll
    for (int j = 0; j < 2; ++j) {
      const int col = bn + tn + j;
      const int half = col >> 9, h = (col >> 6) & 7, d = col & 63;
      float* dst = half ? kavg : qavg;
      dst[(((size_t)b * H + h) * Nr + n) * Dh + d] = acc[i][j] + bias[col];
    }
  }
}

// ---------------------------------------------------------------------------
// Region scores + top-8, barrier-free: 1 wave per (b,h,nq); lane owns regions
// {lane, lane+64}; u64-packed shfl max-reduce (tie -> lowest index).
// ---------------------------------------------------------------------------
__global__ __launch_bounds__(64) void topk_kernel(
    const float* __restrict__ qavg, const float* __restrict__ kavg,
    int* __restrict__ topk) {
  const int blk = blockIdx.x;       // bh*Nr + nq
  const int bh  = blk >> 7;
  const int lane = threadIdx.x;
  const float qv = qavg[(size_t)blk * Dh + lane];
  const float4* k0p = (const float4*)(kavg + ((size_t)bh * Nr + lane) * Dh);
  const float4* k1p = (const float4*)(kavg + ((size_t)bh * Nr + lane + 64) * Dh);
  float d0 = 0.f, d1 = 0.f;
#pragma unroll
  for (int j = 0; j < 16; ++j) {
    const float4 a = k0p[j];
    const float4 bq = k1p[j];
    const float q0 = __shfl(qv, 4 * j + 0);
    const float q1 = __shfl(qv, 4 * j + 1);
    const float q2 = __shfl(qv, 4 * j + 2);
    const float q3 = __shfl(qv, 4 * j + 3);
    d0 += q0 * a.x;  d0 += q1 * a.y;  d0 += q2 * a.z;  d0 += q3 * a.w;
    d1 += q0 * bq.x; d1 += q1 * bq.y; d1 += q2 * bq.z; d1 += q3 * bq.w;
  }
  float v0 = d0, v1 = d1;
#pragma unroll
  for (int j = 0; j < K; ++j) {
    const unsigned long long c0 =
        ((unsigned long long)fkey(v0) << 32) | (unsigned)(127 - lane);
    const unsigned long long c1 =
        ((unsigned long long)fkey(v1) << 32) | (unsigned)(63 - lane);
    unsigned long long c = (c0 > c1) ? c0 : c1;
#pragma unroll
    for (int off = 1; off < 64; off <<= 1) {
      const unsigned long long o = __shfl_xor(c, off);
      c = (o > c) ? o : c;
    }
    const int idx = 127 - (int)(c & 0xffffffffu);
    if (lane == j) topk[blk * K + j] = idx;
    if (idx == lane) v0 = -INFINITY;
    if (idx == lane + 64) v1 = -INFINITY;
  }
}

// ---------------------------------------------------------------------------
// MFMA block-sparse attention: 1 wave per (bh, n). No LDS.
// ---------------------------------------------------------------------------
__global__ __launch_bounds__(64) void attn_mfma_kernel(
    const unsigned short* __restrict__ qbf, const unsigned short* __restrict__ kbf,
    const unsigned short* __restrict__ vt, const int* __restrict__ topk,
    unsigned short* __restrict__ aoutbf) {
  const int phys = blockIdx.x;
  const int blk = (phys & 7) * 512 + (phys >> 3);
  const int bh = blk >> 7, n = blk & (Nr - 1);
  const int b = bh >> 3, h = bh & 7;
  const int lane = threadIdx.x;
  const int q = lane & 15, kg = lane >> 4;
  const int kg1 = kg & 1, kgh = kg >> 1;

  const int rv = topk[blk * K + (lane & 7)];
  int ridx[8];
#pragma unroll
  for (int j = 0; j < 8; ++j) ridx[j] = __shfl(rv, j);

  const unsigned short* qp = qbf + ((size_t)bh * T + n * R + q) * Dh + kg * 8;
  const bf16x8 qf0 = *(const bf16x8*)(qp);
  const bf16x8 qf1 = *(const bf16x8*)(qp + 32);

  f32x4 s[8];
#pragma unroll
  for (int j = 0; j < 8; ++j) {
    const unsigned short* kp = kbf + ((size_t)bh * T + ridx[j] * R + q) * Dh + kg * 8;
    const bf16x8 kf0 = *(const bf16x8*)(kp);
    const bf16x8 kf1 = *(const bf16x8*)(kp + 32);
    f32x4 acc = {};
    acc = __builtin_amdgcn_mfma_f32_16x16x32_bf16(kf0, qf0, acc, 0, 0, 0);
    acc = __builtin_amdgcn_mfma_f32_16x16x32_bf16(kf1, qf1, acc, 0, 0, 0);
    s[j] = acc;
  }

  float mx = s[0][0];
#pragma unroll
  for (int j = 0; j < 8; ++j)
#pragma unroll
    for (int r = 0; r < 4; ++r) mx = fmaxf(mx, s[j][r]);
  mx = fmaxf(mx, __shfl_xor(mx, 16));
  mx = fmaxf(mx, __shfl_xor(mx, 32));
  float sum = 0.f;
#pragma unroll
  for (int j = 0; j < 8; ++j)
#pragma unroll
    for (int r = 0; r < 4; ++r) {
      const float e = __expf((s[j][r] - mx) * SCALE);
      s[j][r] = e; sum += e;
    }
  sum += __shfl_xor(sum, 16);
  sum += __shfl_xor(sum, 32);

  unsigned pk0[8], pk1[8];
#pragma unroll
  for (int j = 0; j < 8; ++j) {
    pk0[j] = cvt_pk_bf16(s[j][0], s[j][1]);
    pk1[j] = cvt_pk_bf16(s[j][2], s[j][3]);
  }

  const int srcA = kg1 * 32 + q;
  const int srcB = kg1 * 32 + 16 + q;
  f32x4 o[4] = {};
#pragma unroll
  for (int t = 0; t < 4; ++t) {
    const unsigned aa0 = __shfl((int)pk0[2 * t], srcA), aa1 = __shfl((int)pk0[2 * t + 1], srcA);
    const unsigned ab0 = __shfl((int)pk1[2 * t], srcA), ab1 = __shfl((int)pk1[2 * t + 1], srcA);
    const unsigned ba0 = __shfl((int)pk0[2 * t], srcB), ba1 = __shfl((int)pk0[2 * t + 1], srcB);
    const unsigned bb0 = __shfl((int)pk1[2 * t], srcB), bb1 = __shfl((int)pk1[2 * t + 1], srcB);
    union { uint4 u; bf16x8 v; } bu;
    bu.u.x = kgh ? aa1 : aa0;
    bu.u.y = kgh ? ab1 : ab0;
    bu.u.z = kgh ? ba1 : ba0;
    bu.u.w = kgh ? bb1 : bb0;
    const int reg = kgh ? ridx[2 * t + 1] : ridx[2 * t];
    const size_t tok = (size_t)reg * R + kg1 * 8;
#pragma unroll
    for (int dt = 0; dt < 4; ++dt) {
      const bf16x8 af = *(const bf16x8*)(vt + ((size_t)bh * Dh + 16 * dt + q) * T + tok);
      o[dt] = __builtin_amdgcn_mfma_f32_16x16x32_bf16(af, bu.v, o[dt], 0, 0, 0);
    }
  }

  const float inv = 1.0f / sum;
  unsigned short* dst = aoutbf + ((size_t)b * T + n * R + q) * C + h * Dh;
#pragma unroll
  for (int dt = 0; dt < 4; ++dt) {
    const unsigned plo = cvt_pk_bf16(o[dt][0] * inv, o[dt][1] * inv);
    const unsigned phi = cvt_pk_bf16(o[dt][2] * inv, o[dt][3] * inv);
    uint2 st; st.x = plo; st.y = phi;
    *(uint2*)(dst + 16 * dt + kg * 4) = st;
  }
}

extern "C" void kernel_launch(void* const* d_in, const int* in_sizes, int n_in,
                              void* d_out, int out_size, void* d_ws, size_t ws_size,
                              hipStream_t stream) {
  const float* x    = (const float*)d_in[0];
  const float* Wqkv = (const float*)d_in[1];
  const float* bqkv = (const float*)d_in[2];
  const float* Wout = (const float*)d_in[3];
  const float* bout = (const float*)d_in[4];
  float* out = (float*)d_out;

  float* ws = (float*)d_ws;
  const size_t bhtd = (size_t)B * H * T * Dh;     // 4,194,304
  const size_t navg = (size_t)B * H * Nr * Dh;    // 262,144
  float* qavg = ws;
  float* kavg = qavg + navg;
  float* xavg = kavg + navg;                       // B*Nr*C
  unsigned short* qbf    = (unsigned short*)(xavg + navg);
  unsigned short* kbf    = qbf + bhtd;
  unsigned short* vt     = kbf + bhtd;
  unsigned short* xbf    = vt + bhtd;
  unsigned short* wqkvt  = xbf + bhtd;
  unsigned short* woutt  = wqkvt + (size_t)QKV_N * KD;
  unsigned short* aoutbf = woutt + (size_t)C * KD;
  int* topk = (int*)(aoutbf + bhtd);

  convert_x_kernel<<<4096, 256, 0, stream>>>((const float4*)x, (ushort4*)xbf);
  transpose_convert_kernel<<<dim3(QKV_N / 32, KD / 32), 256, 0, stream>>>(Wqkv, wqkvt, KD, QKV_N);
  transpose_convert_kernel<<<dim3(C / 32, KD / 32), 256, 0, stream>>>(Wout, woutt, KD, C);
  x_avg_kernel<<<B * Nr, 256, 0, stream>>>(x, xavg);
  qkavg_gemm_kernel<<<dim3(1024 / 64, (B * Nr) / 64), 512, 0, stream>>>(xavg, Wqkv, bqkv, qavg, kavg);
  topk_kernel<<<B * H * Nr, 64, 0, stream>>>(qavg, kavg, topk);
  qkv_gemm_mfma_kernel<<<QKV_N / 128 * (BT / 128), 256, 0, stream>>>(xbf, wqkvt, bqkv, qbf, kbf, vt);
  attn_mfma_kernel<<<B * H * Nr, 64, 0, stream>>>(qbf, kbf, vt, topk, aoutbf);
  out_gemm_mfma_kernel<<<C / 128 * (BT / 128), 256, 0, stream>>>(aoutbf, woutt, bout, out);
}